// Round 4
// baseline (216.239 us; speedup 1.0000x reference)
//
#include <hip/hip_runtime.h>
#include <hip/hip_bf16.h>
#include <stdint.h>

// GCN 2-layer + linear head. fp32 accumulate, bf16 intermediate node tables
// (hs1/h1post/hs2) to halve gather-table footprint + L2<-L3 fill traffic.
// CSR build = two-level bucket counting sort (no scattered global atomics).

#define THREADS 256
#define NBUCK_MAX 1024
#define SORT_BLOCKS 200
#define CAP 4096

__device__ __forceinline__ unsigned int pack_bf2(float a, float b) {
    unsigned int ua = __float_as_uint(a);
    unsigned int ub = __float_as_uint(b);
    ua = (ua + 0x7FFFu + ((ua >> 16) & 1u)) >> 16;
    ub = (ub + 0x7FFFu + ((ub >> 16) & 1u)) >> 16;
    return ua | (ub << 16);
}
__device__ __forceinline__ float bf_lo(unsigned int u) { return __uint_as_float(u << 16); }
__device__ __forceinline__ float bf_hi(unsigned int u) { return __uint_as_float(u & 0xFFFF0000u); }

__global__ void k_detect_dtype(const unsigned int* ei_words, int* flag) {
    int is64 = 1;
    for (int i = 1; i < 64; i += 2) {
        if (ei_words[i] != 0u) { is64 = 0; break; }
    }
    *flag = is64;
}

__global__ void k_zero_int(int* p, int n) {
    int i = blockIdx.x * blockDim.x + threadIdx.x;
    if (i < n) p[i] = 0;
}

__global__ void k_bucket_hist(const void* ei, const int* flag, int* bucket_count, int E, int B) {
    __shared__ int h[NBUCK_MAX];
    int t = threadIdx.x;
    for (int i = t; i < B; i += THREADS) h[i] = 0;
    __syncthreads();
    int chunk = (E + gridDim.x - 1) / gridDim.x;
    int lo = blockIdx.x * chunk;
    int hi = min(lo + chunk, E);
    bool is64 = (*flag != 0);
    const long long* p64 = (const long long*)ei;
    const int* p32 = (const int*)ei;
    for (int e = lo + t; e < hi; e += THREADS) {
        int d = is64 ? (int)p64[(size_t)E + e] : p32[E + e];
        atomicAdd(&h[d >> 7], 1);
    }
    __syncthreads();
    for (int i = t; i < B; i += THREADS) {
        int c = h[i];
        if (c) atomicAdd(&bucket_count[i], c);
    }
}

__global__ void k_bucket_scan(const int* bucket_count, int* bucket_base, int* bucket_cursor, int B) {
    __shared__ int s[1024];
    int t = threadIdx.x;
    int c = (t < B) ? bucket_count[t] : 0;
    s[t] = c;
    __syncthreads();
    for (int off = 1; off < 1024; off <<= 1) {
        int v = (t >= off) ? s[t - off] : 0;
        __syncthreads();
        s[t] += v;
        __syncthreads();
    }
    if (t < B) {
        int b = s[t] - c;
        bucket_base[t] = b;
        bucket_cursor[t] = b;
    }
}

__global__ void k_bucket_scatter(const void* ei, const int* flag, int* bucket_cursor,
                                 unsigned int* packed, int E, int B) {
    __shared__ int h[NBUCK_MAX];
    __shared__ int base[NBUCK_MAX];
    int t = threadIdx.x;
    for (int i = t; i < B; i += THREADS) h[i] = 0;
    __syncthreads();
    int chunk = (E + gridDim.x - 1) / gridDim.x;
    int lo = blockIdx.x * chunk;
    int hi = min(lo + chunk, E);
    bool is64 = (*flag != 0);
    const long long* p64 = (const long long*)ei;
    const int* p32 = (const int*)ei;
    for (int e = lo + t; e < hi; e += THREADS) {
        int d = is64 ? (int)p64[(size_t)E + e] : p32[E + e];
        atomicAdd(&h[d >> 7], 1);
    }
    __syncthreads();
    for (int i = t; i < B; i += THREADS) {
        int c = h[i];
        base[i] = c ? atomicAdd(&bucket_cursor[i], c) : 0;
    }
    __syncthreads();
    for (int i = t; i < B; i += THREADS) h[i] = 0;
    __syncthreads();
    for (int e = lo + t; e < hi; e += THREADS) {
        int srcv, d;
        if (is64) { srcv = (int)p64[e]; d = (int)p64[(size_t)E + e]; }
        else      { srcv = p32[e];      d = p32[E + e]; }
        int b = d >> 7;
        int pos = base[b] + atomicAdd(&h[b], 1);
        packed[pos] = (unsigned int)srcv | ((unsigned int)(d & 127) << 25);
    }
}

__global__ void k_fine_sort(const unsigned int* __restrict__ packed,
                            const int* __restrict__ bucket_base,
                            const int* __restrict__ bucket_count_arr,
                            int* __restrict__ csr, int* __restrict__ offsets,
                            int* __restrict__ countp, float* __restrict__ dinv,
                            int n, int B) {
    __shared__ unsigned int words[CAP];
    __shared__ int srcstage[CAP];
    __shared__ int cnt[128];
    __shared__ int scanv[128];
    __shared__ int cursor[128];
    int b = blockIdx.x;
    int t = threadIdx.x;
    int base = bucket_base[b];
    int size = bucket_count_arr[b];
    if (t < 128) cnt[t] = 0;
    __syncthreads();
    for (int i0 = 0; i0 < size; i0 += THREADS) {
        int i = i0 + t;
        if (i < size) {
            unsigned int w = packed[base + i];
            if (i < CAP) words[i] = w;
            atomicAdd(&cnt[(w >> 25) & 127], 1);
        }
    }
    __syncthreads();
    if (t < 128) scanv[t] = cnt[t];
    __syncthreads();
    for (int off = 1; off < 128; off <<= 1) {
        int v = 0;
        if (t < 128 && t >= off) v = scanv[t - off];
        __syncthreads();
        if (t < 128) scanv[t] += v;
        __syncthreads();
    }
    if (t < 128) {
        int ex = scanv[t] - cnt[t];
        scanv[t] = ex;
        cursor[t] = ex;
        int node = (b << 7) + t;
        if (node < n) {
            offsets[node] = base + ex;
            countp[node] = cnt[t];
            dinv[node] = rsqrtf((float)(cnt[t] + 1));
        }
    }
    __syncthreads();
    if (size <= CAP) {
        for (int i0 = 0; i0 < size; i0 += THREADS) {
            int i = i0 + t;
            if (i < size) {
                unsigned int w = words[i];
                int d = (w >> 25) & 127;
                int rank = atomicAdd(&cursor[d], 1);
                srcstage[rank] = (int)(w & 0x1FFFFFFu);
            }
        }
        __syncthreads();
        for (int i0 = 0; i0 < size; i0 += THREADS) {
            int i = i0 + t;
            if (i < size) csr[base + i] = srcstage[i];
        }
    } else {
        for (int i0 = 0; i0 < size; i0 += THREADS) {
            int i = i0 + t;
            if (i < size) {
                unsigned int w = packed[base + i];
                int d = (w >> 25) & 127;
                int rank = atomicAdd(&cursor[d], 1);
                csr[base + rank] = (int)(w & 0x1FFFFFFu);
            }
        }
    }
}

// hs1[r][:] = bf16( dinv[r] * (x[r] @ W1) )   (x: [n,128], W1: [128,64])
__global__ void __launch_bounds__(THREADS, 2) k_gemm1(const float* __restrict__ x,
                                                      const float* __restrict__ W1,
                                                      const float* __restrict__ dinv,
                                                      unsigned int* __restrict__ hs1, int n) {
    __shared__ float Ws[128 * 64];
    int t = threadIdx.x;
    #pragma unroll
    for (int i = 0; i < 8; ++i) {
        int idx = t + i * THREADS;
        ((float4*)Ws)[idx] = ((const float4*)W1)[idx];
    }
    __syncthreads();

    int r = blockIdx.x * THREADS + t;
    if (r >= n) return;

    float4 acc[16];
    #pragma unroll
    for (int j = 0; j < 16; ++j) acc[j] = make_float4(0.f, 0.f, 0.f, 0.f);

    const float* xrow = x + (size_t)r * 128;
    for (int kk = 0; kk < 128; kk += 32) {
        float4 xv[8];
        #pragma unroll
        for (int q = 0; q < 8; ++q) xv[q] = ((const float4*)(xrow + kk))[q];
        #pragma unroll
        for (int c = 0; c < 32; ++c) {
            const float4 v = xv[c >> 2];
            const int m = c & 3;
            const float xc = (m == 0) ? v.x : (m == 1) ? v.y : (m == 2) ? v.z : v.w;
            const float4* wrow = (const float4*)(Ws + (kk + c) * 64);
            #pragma unroll
            for (int j = 0; j < 16; ++j) {
                float4 w = wrow[j];
                acc[j].x = fmaf(xc, w.x, acc[j].x);
                acc[j].y = fmaf(xc, w.y, acc[j].y);
                acc[j].z = fmaf(xc, w.z, acc[j].z);
                acc[j].w = fmaf(xc, w.w, acc[j].w);
            }
        }
    }
    float dv = dinv[r];
    unsigned int* orow = hs1 + (size_t)r * 32;      // 64 bf16 = 32 uints
    #pragma unroll
    for (int j = 0; j < 16; ++j) {
        float4 a = acc[j];
        orow[2 * j]     = pack_bf2(a.x * dv, a.y * dv);
        orow[2 * j + 1] = pack_bf2(a.z * dv, a.w * dv);
    }
}

// One wave per node. 4 edge-groups x 16 lanes x (4 bf16 = 8B), unrolled x2.
__global__ void k_agg1(const unsigned int* __restrict__ hs1, const int* __restrict__ csr,
                       const int* __restrict__ offsets, const int* __restrict__ count,
                       const float* __restrict__ dinv, const float* __restrict__ b1,
                       unsigned int* __restrict__ h1post, int n) {
    int wid = threadIdx.x >> 6;
    int lane = threadIdx.x & 63;
    int node = blockIdx.x * 4 + wid;
    if (node >= n) return;
    int g  = lane >> 4;
    int f4 = lane & 15;                 // uint2 index within 64-bf16 row
    int s = offsets[node];
    int c = count[node];
    const uint2* tab = (const uint2*)hs1;   // row stride = 16 uint2

    float4 a0 = make_float4(0.f, 0.f, 0.f, 0.f);
    float4 a1 = make_float4(0.f, 0.f, 0.f, 0.f);
    if (g == 0) {
        uint2 sv = tab[(size_t)node * 16 + f4];
        a0 = make_float4(bf_lo(sv.x), bf_hi(sv.x), bf_lo(sv.y), bf_hi(sv.y));
    }

    for (int j = 0; j < c; j += 8) {
        int e0 = j + g;
        int e1 = j + 4 + g;
        int i0 = s + min(e0, c - 1);
        int i1 = s + min(e1, c - 1);
        int s0 = csr[i0];
        int s1 = csr[i1];
        float m0 = (e0 < c) ? 1.f : 0.f;
        float m1 = (e1 < c) ? 1.f : 0.f;
        uint2 u0 = tab[(size_t)s0 * 16 + f4];
        uint2 u1 = tab[(size_t)s1 * 16 + f4];
        a0.x = fmaf(m0, bf_lo(u0.x), a0.x); a0.y = fmaf(m0, bf_hi(u0.x), a0.y);
        a0.z = fmaf(m0, bf_lo(u0.y), a0.z); a0.w = fmaf(m0, bf_hi(u0.y), a0.w);
        a1.x = fmaf(m1, bf_lo(u1.x), a1.x); a1.y = fmaf(m1, bf_hi(u1.x), a1.y);
        a1.z = fmaf(m1, bf_lo(u1.y), a1.z); a1.w = fmaf(m1, bf_hi(u1.y), a1.w);
    }
    a0.x += a1.x; a0.y += a1.y; a0.z += a1.z; a0.w += a1.w;
    a0.x += __shfl_xor(a0.x, 16); a0.y += __shfl_xor(a0.y, 16);
    a0.z += __shfl_xor(a0.z, 16); a0.w += __shfl_xor(a0.w, 16);
    a0.x += __shfl_xor(a0.x, 32); a0.y += __shfl_xor(a0.y, 32);
    a0.z += __shfl_xor(a0.z, 32); a0.w += __shfl_xor(a0.w, 32);

    if (g == 0) {
        float dv = dinv[node];
        float4 b = ((const float4*)b1)[f4];
        float ox = fmaxf(fmaf(dv, a0.x, b.x), 0.f);
        float oy = fmaxf(fmaf(dv, a0.y, b.y), 0.f);
        float oz = fmaxf(fmaf(dv, a0.z, b.z), 0.f);
        float ow = fmaxf(fmaf(dv, a0.w, b.w), 0.f);
        uint2 o;
        o.x = pack_bf2(ox, oy);
        o.y = pack_bf2(oz, ow);
        ((uint2*)h1post)[(size_t)node * 16 + f4] = o;
    }
}

// hs2[r][:] = bf16( dinv[r] * (h1post[r] @ W2) )   (W2: [64,32])
__global__ void __launch_bounds__(THREADS, 2) k_gemm2(const unsigned int* __restrict__ h1,
                                                      const float* __restrict__ W2,
                                                      const float* __restrict__ dinv,
                                                      unsigned int* __restrict__ hs2, int n) {
    __shared__ float Ws[64 * 32];
    int t = threadIdx.x;
    #pragma unroll
    for (int i = 0; i < 2; ++i) {
        int idx = t + i * THREADS;
        ((float4*)Ws)[idx] = ((const float4*)W2)[idx];
    }
    __syncthreads();

    int r = blockIdx.x * THREADS + t;
    if (r >= n) return;

    float xs[64];
    const uint4* xrow = (const uint4*)(h1 + (size_t)r * 32);  // 64 bf16 = 8 uint4
    #pragma unroll
    for (int q = 0; q < 8; ++q) {
        uint4 u = xrow[q];
        xs[8 * q + 0] = bf_lo(u.x); xs[8 * q + 1] = bf_hi(u.x);
        xs[8 * q + 2] = bf_lo(u.y); xs[8 * q + 3] = bf_hi(u.y);
        xs[8 * q + 4] = bf_lo(u.z); xs[8 * q + 5] = bf_hi(u.z);
        xs[8 * q + 6] = bf_lo(u.w); xs[8 * q + 7] = bf_hi(u.w);
    }

    float4 acc[8];
    #pragma unroll
    for (int j = 0; j < 8; ++j) acc[j] = make_float4(0.f, 0.f, 0.f, 0.f);

    #pragma unroll
    for (int k = 0; k < 64; ++k) {
        const float xc = xs[k];
        const float4* wrow = (const float4*)(Ws + k * 32);
        #pragma unroll
        for (int j = 0; j < 8; ++j) {
            float4 w = wrow[j];
            acc[j].x = fmaf(xc, w.x, acc[j].x);
            acc[j].y = fmaf(xc, w.y, acc[j].y);
            acc[j].z = fmaf(xc, w.z, acc[j].z);
            acc[j].w = fmaf(xc, w.w, acc[j].w);
        }
    }
    float dv = dinv[r];
    unsigned int* orow = hs2 + (size_t)r * 16;      // 32 bf16 = 16 uints
    #pragma unroll
    for (int j = 0; j < 8; ++j) {
        float4 a = acc[j];
        orow[2 * j]     = pack_bf2(a.x * dv, a.y * dv);
        orow[2 * j + 1] = pack_bf2(a.z * dv, a.w * dv);
    }
}

// One wave per node. 8 edge-groups x 8 lanes x (4 bf16 = 8B), unrolled x2. Fused head.
__global__ void k_agg2_head(const unsigned int* __restrict__ hs2, const int* __restrict__ csr,
                            const int* __restrict__ offsets, const int* __restrict__ count,
                            const float* __restrict__ dinv, const float* __restrict__ b2,
                            const float* __restrict__ Wfc, const float* __restrict__ bfc,
                            float* __restrict__ out, int n) {
    int wid = threadIdx.x >> 6;
    int lane = threadIdx.x & 63;
    int node = blockIdx.x * 4 + wid;
    if (node >= n) return;
    int g  = lane >> 3;
    int f4 = lane & 7;                  // uint2 index within 32-bf16 row
    int s = offsets[node];
    int c = count[node];
    const uint2* tab = (const uint2*)hs2;   // row stride = 8 uint2

    float4 a0 = make_float4(0.f, 0.f, 0.f, 0.f);
    float4 a1 = make_float4(0.f, 0.f, 0.f, 0.f);
    if (g == 0) {
        uint2 sv = tab[(size_t)node * 8 + f4];
        a0 = make_float4(bf_lo(sv.x), bf_hi(sv.x), bf_lo(sv.y), bf_hi(sv.y));
    }

    for (int j = 0; j < c; j += 16) {
        int e0 = j + g;
        int e1 = j + 8 + g;
        int i0 = s + min(e0, c - 1);
        int i1 = s + min(e1, c - 1);
        int s0 = csr[i0];
        int s1 = csr[i1];
        float m0 = (e0 < c) ? 1.f : 0.f;
        float m1 = (e1 < c) ? 1.f : 0.f;
        uint2 u0 = tab[(size_t)s0 * 8 + f4];
        uint2 u1 = tab[(size_t)s1 * 8 + f4];
        a0.x = fmaf(m0, bf_lo(u0.x), a0.x); a0.y = fmaf(m0, bf_hi(u0.x), a0.y);
        a0.z = fmaf(m0, bf_lo(u0.y), a0.z); a0.w = fmaf(m0, bf_hi(u0.y), a0.w);
        a1.x = fmaf(m1, bf_lo(u1.x), a1.x); a1.y = fmaf(m1, bf_hi(u1.x), a1.y);
        a1.z = fmaf(m1, bf_lo(u1.y), a1.z); a1.w = fmaf(m1, bf_hi(u1.y), a1.w);
    }
    a0.x += a1.x; a0.y += a1.y; a0.z += a1.z; a0.w += a1.w;
    #pragma unroll
    for (int m = 8; m <= 32; m <<= 1) {
        a0.x += __shfl_xor(a0.x, m); a0.y += __shfl_xor(a0.y, m);
        a0.z += __shfl_xor(a0.z, m); a0.w += __shfl_xor(a0.w, m);
    }

    float dv = dinv[node];
    float4 b = ((const float4*)b2)[f4];
    float4 w = ((const float4*)Wfc)[f4];
    float hx = fmaxf(fmaf(dv, a0.x, b.x), 0.f);
    float hy = fmaxf(fmaf(dv, a0.y, b.y), 0.f);
    float hz = fmaxf(fmaf(dv, a0.z, b.z), 0.f);
    float hw = fmaxf(fmaf(dv, a0.w, b.w), 0.f);
    float p = hx * w.x + hy * w.y + hz * w.z + hw * w.w;
    p += __shfl_xor(p, 1);
    p += __shfl_xor(p, 2);
    p += __shfl_xor(p, 4);
    if (lane == 0) out[node] = p + bfc[0];
}

extern "C" void kernel_launch(void* const* d_in, const int* in_sizes, int n_in,
                              void* d_out, int out_size, void* d_ws, size_t ws_size,
                              hipStream_t stream) {
    const float* x   = (const float*)d_in[0];
    const void*  ei  = d_in[1];
    const float* W1  = (const float*)d_in[2];
    const float* b1  = (const float*)d_in[3];
    const float* W2  = (const float*)d_in[4];
    const float* b2  = (const float*)d_in[5];
    const float* Wfc = (const float*)d_in[6];
    const float* bfc = (const float*)d_in[7];
    float* out = (float*)d_out;

    const int n = in_sizes[0] / 128;                 // 100000
    const int E = in_sizes[1] / 2;                   // 1600000
    const int B = (n + 127) >> 7;                    // 782 buckets

    size_t off = 0;
    auto alloc = [&](size_t bytes) -> void* {
        void* p = (char*)d_ws + off;
        off += (bytes + 255) & ~(size_t)255;
        return p;
    };
    int*   bucket_count  = (int*)alloc((size_t)NBUCK_MAX * 4);
    int*   bucket_base   = (int*)alloc((size_t)NBUCK_MAX * 4);
    int*   bucket_cursor = (int*)alloc((size_t)NBUCK_MAX * 4);
    unsigned int* packed = (unsigned int*)alloc((size_t)E * 4);
    int*   csr     = (int*)  alloc((size_t)E * 4);
    int*   offsets = (int*)  alloc((size_t)n * 4);
    int*   count   = (int*)  alloc((size_t)n * 4);
    float* dinv    = (float*)alloc((size_t)n * 4);
    unsigned int* hs1    = (unsigned int*)alloc((size_t)n * 64 * 2);  // bf16
    unsigned int* h1post = (unsigned int*)alloc((size_t)n * 64 * 2);  // bf16
    unsigned int* hs2    = (unsigned int*)alloc((size_t)n * 32 * 2);  // bf16
    int*   flag    = (int*)  alloc(4);
    (void)ws_size;

    const int NB = (n + THREADS - 1) / THREADS;
    const int AG = (n + 3) / 4;

    k_detect_dtype<<<1, 1, 0, stream>>>((const unsigned int*)ei, flag);
    k_zero_int<<<(B + THREADS - 1) / THREADS, THREADS, 0, stream>>>(bucket_count, B);
    k_bucket_hist<<<SORT_BLOCKS, THREADS, 0, stream>>>(ei, flag, bucket_count, E, B);
    k_bucket_scan<<<1, 1024, 0, stream>>>(bucket_count, bucket_base, bucket_cursor, B);
    k_bucket_scatter<<<SORT_BLOCKS, THREADS, 0, stream>>>(ei, flag, bucket_cursor, packed, E, B);
    k_fine_sort<<<B, THREADS, 0, stream>>>(packed, bucket_base, bucket_count,
                                           csr, offsets, count, dinv, n, B);
    k_gemm1<<<NB, THREADS, 0, stream>>>(x, W1, dinv, hs1, n);
    k_agg1<<<AG, THREADS, 0, stream>>>(hs1, csr, offsets, count, dinv, b1, h1post, n);
    k_gemm2<<<NB, THREADS, 0, stream>>>(h1post, W2, dinv, hs2, n);
    k_agg2_head<<<AG, THREADS, 0, stream>>>(hs2, csr, offsets, count, dinv, b2, Wfc, bfc, out, n);
}

// Round 5
// 210.441 us; speedup vs baseline: 1.0276x; 1.0276x over previous
//
#include <hip/hip_runtime.h>
#include <hip/hip_bf16.h>
#include <stdint.h>

// GCN 2-layer + linear head. fp32 accumulate, bf16 intermediate node tables.
// CSR build = two-level bucket counting sort (no scattered global atomics).
// GEMMs column-split (gridDim.y=2) to fix grid-size-limited occupancy.

#define THREADS 256
#define NBUCK_MAX 1024
#define SORT_BLOCKS 200
#define CAP 4096

__device__ __forceinline__ unsigned int pack_bf2(float a, float b) {
    unsigned int ua = __float_as_uint(a);
    unsigned int ub = __float_as_uint(b);
    ua = (ua + 0x7FFFu + ((ua >> 16) & 1u)) >> 16;
    ub = (ub + 0x7FFFu + ((ub >> 16) & 1u)) >> 16;
    return ua | (ub << 16);
}
__device__ __forceinline__ float bf_lo(unsigned int u) { return __uint_as_float(u << 16); }
__device__ __forceinline__ float bf_hi(unsigned int u) { return __uint_as_float(u & 0xFFFF0000u); }

__global__ void k_detect_dtype(const unsigned int* ei_words, int* flag) {
    int is64 = 1;
    for (int i = 1; i < 64; i += 2) {
        if (ei_words[i] != 0u) { is64 = 0; break; }
    }
    *flag = is64;
}

__global__ void k_zero_int(int* p, int n) {
    int i = blockIdx.x * blockDim.x + threadIdx.x;
    if (i < n) p[i] = 0;
}

__global__ void k_bucket_hist(const void* ei, const int* flag, int* bucket_count, int E, int B) {
    __shared__ int h[NBUCK_MAX];
    int t = threadIdx.x;
    for (int i = t; i < B; i += THREADS) h[i] = 0;
    __syncthreads();
    int chunk = (E + gridDim.x - 1) / gridDim.x;
    int lo = blockIdx.x * chunk;
    int hi = min(lo + chunk, E);
    bool is64 = (*flag != 0);
    const long long* p64 = (const long long*)ei;
    const int* p32 = (const int*)ei;
    for (int e = lo + t; e < hi; e += THREADS) {
        int d = is64 ? (int)p64[(size_t)E + e] : p32[E + e];
        atomicAdd(&h[d >> 7], 1);
    }
    __syncthreads();
    for (int i = t; i < B; i += THREADS) {
        int c = h[i];
        if (c) atomicAdd(&bucket_count[i], c);
    }
}

__global__ void k_bucket_scan(const int* bucket_count, int* bucket_base, int* bucket_cursor, int B) {
    __shared__ int s[1024];
    int t = threadIdx.x;
    int c = (t < B) ? bucket_count[t] : 0;
    s[t] = c;
    __syncthreads();
    for (int off = 1; off < 1024; off <<= 1) {
        int v = (t >= off) ? s[t - off] : 0;
        __syncthreads();
        s[t] += v;
        __syncthreads();
    }
    if (t < B) {
        int b = s[t] - c;
        bucket_base[t] = b;
        bucket_cursor[t] = b;
    }
}

__global__ void k_bucket_scatter(const void* ei, const int* flag, int* bucket_cursor,
                                 unsigned int* packed, int E, int B) {
    __shared__ int h[NBUCK_MAX];
    __shared__ int base[NBUCK_MAX];
    int t = threadIdx.x;
    for (int i = t; i < B; i += THREADS) h[i] = 0;
    __syncthreads();
    int chunk = (E + gridDim.x - 1) / gridDim.x;
    int lo = blockIdx.x * chunk;
    int hi = min(lo + chunk, E);
    bool is64 = (*flag != 0);
    const long long* p64 = (const long long*)ei;
    const int* p32 = (const int*)ei;
    for (int e = lo + t; e < hi; e += THREADS) {
        int d = is64 ? (int)p64[(size_t)E + e] : p32[E + e];
        atomicAdd(&h[d >> 7], 1);
    }
    __syncthreads();
    for (int i = t; i < B; i += THREADS) {
        int c = h[i];
        base[i] = c ? atomicAdd(&bucket_cursor[i], c) : 0;
    }
    __syncthreads();
    for (int i = t; i < B; i += THREADS) h[i] = 0;
    __syncthreads();
    for (int e = lo + t; e < hi; e += THREADS) {
        int srcv, d;
        if (is64) { srcv = (int)p64[e]; d = (int)p64[(size_t)E + e]; }
        else      { srcv = p32[e];      d = p32[E + e]; }
        int b = d >> 7;
        int pos = base[b] + atomicAdd(&h[b], 1);
        packed[pos] = (unsigned int)srcv | ((unsigned int)(d & 127) << 25);
    }
}

__global__ void k_fine_sort(const unsigned int* __restrict__ packed,
                            const int* __restrict__ bucket_base,
                            const int* __restrict__ bucket_count_arr,
                            int* __restrict__ csr, int* __restrict__ offsets,
                            int* __restrict__ countp, float* __restrict__ dinv,
                            int n, int B) {
    __shared__ unsigned int words[CAP];
    __shared__ int srcstage[CAP];
    __shared__ int cnt[128];
    __shared__ int scanv[128];
    __shared__ int cursor[128];
    int b = blockIdx.x;
    int t = threadIdx.x;
    int base = bucket_base[b];
    int size = bucket_count_arr[b];
    if (t < 128) cnt[t] = 0;
    __syncthreads();
    for (int i0 = 0; i0 < size; i0 += THREADS) {
        int i = i0 + t;
        if (i < size) {
            unsigned int w = packed[base + i];
            if (i < CAP) words[i] = w;
            atomicAdd(&cnt[(w >> 25) & 127], 1);
        }
    }
    __syncthreads();
    if (t < 128) scanv[t] = cnt[t];
    __syncthreads();
    for (int off = 1; off < 128; off <<= 1) {
        int v = 0;
        if (t < 128 && t >= off) v = scanv[t - off];
        __syncthreads();
        if (t < 128) scanv[t] += v;
        __syncthreads();
    }
    if (t < 128) {
        int ex = scanv[t] - cnt[t];
        scanv[t] = ex;
        cursor[t] = ex;
        int node = (b << 7) + t;
        if (node < n) {
            offsets[node] = base + ex;
            countp[node] = cnt[t];
            dinv[node] = rsqrtf((float)(cnt[t] + 1));
        }
    }
    __syncthreads();
    if (size <= CAP) {
        for (int i0 = 0; i0 < size; i0 += THREADS) {
            int i = i0 + t;
            if (i < size) {
                unsigned int w = words[i];
                int d = (w >> 25) & 127;
                int rank = atomicAdd(&cursor[d], 1);
                srcstage[rank] = (int)(w & 0x1FFFFFFu);
            }
        }
        __syncthreads();
        for (int i0 = 0; i0 < size; i0 += THREADS) {
            int i = i0 + t;
            if (i < size) csr[base + i] = srcstage[i];
        }
    } else {
        for (int i0 = 0; i0 < size; i0 += THREADS) {
            int i = i0 + t;
            if (i < size) {
                unsigned int w = packed[base + i];
                int d = (w >> 25) & 127;
                int rank = atomicAdd(&cursor[d], 1);
                csr[base + rank] = (int)(w & 0x1FFFFFFu);
            }
        }
    }
}

// hs1[r][c0+j] = bf16( dinv[r] * sum_k x[r][k] * W1[k][c0+j] ), c0 = blockIdx.y*32.
__global__ void __launch_bounds__(THREADS, 2) k_gemm1(const float* __restrict__ x,
                                                      const float* __restrict__ W1,
                                                      const float* __restrict__ dinv,
                                                      unsigned int* __restrict__ hs1, int n) {
    __shared__ float Ws[128 * 32];
    int t = threadIdx.x;
    int cb = blockIdx.y;                            // 0 or 1: column half
    // stage W1[:, cb*32 .. cb*32+32): 128 rows x 8 float4
    #pragma unroll
    for (int i = 0; i < 4; ++i) {
        int idx = t + i * THREADS;                  // 0..1023
        int k = idx >> 3;
        int c4 = idx & 7;
        ((float4*)Ws)[idx] = ((const float4*)W1)[k * 16 + cb * 8 + c4];
    }
    __syncthreads();

    int r = blockIdx.x * THREADS + t;
    if (r >= n) return;

    float4 acc[8];
    #pragma unroll
    for (int j = 0; j < 8; ++j) acc[j] = make_float4(0.f, 0.f, 0.f, 0.f);

    const float* xrow = x + (size_t)r * 128;
    for (int kk = 0; kk < 128; kk += 32) {
        float4 xv[8];
        #pragma unroll
        for (int q = 0; q < 8; ++q) xv[q] = ((const float4*)(xrow + kk))[q];
        #pragma unroll
        for (int c = 0; c < 32; ++c) {
            const float4 v = xv[c >> 2];
            const int m = c & 3;
            const float xc = (m == 0) ? v.x : (m == 1) ? v.y : (m == 2) ? v.z : v.w;
            const float4* wrow = (const float4*)(Ws + (kk + c) * 32);
            #pragma unroll
            for (int j = 0; j < 8; ++j) {
                float4 w = wrow[j];
                acc[j].x = fmaf(xc, w.x, acc[j].x);
                acc[j].y = fmaf(xc, w.y, acc[j].y);
                acc[j].z = fmaf(xc, w.z, acc[j].z);
                acc[j].w = fmaf(xc, w.w, acc[j].w);
            }
        }
    }
    float dv = dinv[r];
    unsigned int* orow = hs1 + (size_t)r * 32 + cb * 16;   // 32 bf16 = 16 uints
    #pragma unroll
    for (int j = 0; j < 8; ++j) {
        float4 a = acc[j];
        orow[2 * j]     = pack_bf2(a.x * dv, a.y * dv);
        orow[2 * j + 1] = pack_bf2(a.z * dv, a.w * dv);
    }
}

// One wave per node. 4 edge-groups x 16 lanes x (4 bf16 = 8B), unrolled x2.
__global__ void k_agg1(const unsigned int* __restrict__ hs1, const int* __restrict__ csr,
                       const int* __restrict__ offsets, const int* __restrict__ count,
                       const float* __restrict__ dinv, const float* __restrict__ b1,
                       unsigned int* __restrict__ h1post, int n) {
    int wid = threadIdx.x >> 6;
    int lane = threadIdx.x & 63;
    int node = blockIdx.x * 4 + wid;
    if (node >= n) return;
    int g  = lane >> 4;
    int f4 = lane & 15;
    int s = offsets[node];
    int c = count[node];
    const uint2* tab = (const uint2*)hs1;

    float4 a0 = make_float4(0.f, 0.f, 0.f, 0.f);
    float4 a1 = make_float4(0.f, 0.f, 0.f, 0.f);
    if (g == 0) {
        uint2 sv = tab[(size_t)node * 16 + f4];
        a0 = make_float4(bf_lo(sv.x), bf_hi(sv.x), bf_lo(sv.y), bf_hi(sv.y));
    }

    for (int j = 0; j < c; j += 8) {
        int e0 = j + g;
        int e1 = j + 4 + g;
        int i0 = s + min(e0, c - 1);
        int i1 = s + min(e1, c - 1);
        int s0 = csr[i0];
        int s1 = csr[i1];
        float m0 = (e0 < c) ? 1.f : 0.f;
        float m1 = (e1 < c) ? 1.f : 0.f;
        uint2 u0 = tab[(size_t)s0 * 16 + f4];
        uint2 u1 = tab[(size_t)s1 * 16 + f4];
        a0.x = fmaf(m0, bf_lo(u0.x), a0.x); a0.y = fmaf(m0, bf_hi(u0.x), a0.y);
        a0.z = fmaf(m0, bf_lo(u0.y), a0.z); a0.w = fmaf(m0, bf_hi(u0.y), a0.w);
        a1.x = fmaf(m1, bf_lo(u1.x), a1.x); a1.y = fmaf(m1, bf_hi(u1.x), a1.y);
        a1.z = fmaf(m1, bf_lo(u1.y), a1.z); a1.w = fmaf(m1, bf_hi(u1.y), a1.w);
    }
    a0.x += a1.x; a0.y += a1.y; a0.z += a1.z; a0.w += a1.w;
    a0.x += __shfl_xor(a0.x, 16); a0.y += __shfl_xor(a0.y, 16);
    a0.z += __shfl_xor(a0.z, 16); a0.w += __shfl_xor(a0.w, 16);
    a0.x += __shfl_xor(a0.x, 32); a0.y += __shfl_xor(a0.y, 32);
    a0.z += __shfl_xor(a0.z, 32); a0.w += __shfl_xor(a0.w, 32);

    if (g == 0) {
        float dv = dinv[node];
        float4 b = ((const float4*)b1)[f4];
        float ox = fmaxf(fmaf(dv, a0.x, b.x), 0.f);
        float oy = fmaxf(fmaf(dv, a0.y, b.y), 0.f);
        float oz = fmaxf(fmaf(dv, a0.z, b.z), 0.f);
        float ow = fmaxf(fmaf(dv, a0.w, b.w), 0.f);
        uint2 o;
        o.x = pack_bf2(ox, oy);
        o.y = pack_bf2(oz, ow);
        ((uint2*)h1post)[(size_t)node * 16 + f4] = o;
    }
}

// hs2[r][c0+j] = bf16( dinv[r] * sum_k h1[r][k] * W2[k][c0+j] ), c0 = blockIdx.y*16.
__global__ void __launch_bounds__(THREADS, 2) k_gemm2(const unsigned int* __restrict__ h1,
                                                      const float* __restrict__ W2,
                                                      const float* __restrict__ dinv,
                                                      unsigned int* __restrict__ hs2, int n) {
    __shared__ float Ws[64 * 16];
    int t = threadIdx.x;
    int cb = blockIdx.y;
    // stage W2[:, cb*16 .. cb*16+16): 64 rows x 4 float4 = 256 float4
    {
        int k = t >> 2;
        int c4 = t & 3;
        ((float4*)Ws)[t] = ((const float4*)W2)[k * 8 + cb * 4 + c4];
    }
    __syncthreads();

    int r = blockIdx.x * THREADS + t;
    if (r >= n) return;

    float xs[64];
    const uint4* xrow = (const uint4*)(h1 + (size_t)r * 32);
    #pragma unroll
    for (int q = 0; q < 8; ++q) {
        uint4 u = xrow[q];
        xs[8 * q + 0] = bf_lo(u.x); xs[8 * q + 1] = bf_hi(u.x);
        xs[8 * q + 2] = bf_lo(u.y); xs[8 * q + 3] = bf_hi(u.y);
        xs[8 * q + 4] = bf_lo(u.z); xs[8 * q + 5] = bf_hi(u.z);
        xs[8 * q + 6] = bf_lo(u.w); xs[8 * q + 7] = bf_hi(u.w);
    }

    float4 acc[4];
    #pragma unroll
    for (int j = 0; j < 4; ++j) acc[j] = make_float4(0.f, 0.f, 0.f, 0.f);

    #pragma unroll
    for (int k = 0; k < 64; ++k) {
        const float xc = xs[k];
        const float4* wrow = (const float4*)(Ws + k * 16);
        #pragma unroll
        for (int j = 0; j < 4; ++j) {
            float4 w = wrow[j];
            acc[j].x = fmaf(xc, w.x, acc[j].x);
            acc[j].y = fmaf(xc, w.y, acc[j].y);
            acc[j].z = fmaf(xc, w.z, acc[j].z);
            acc[j].w = fmaf(xc, w.w, acc[j].w);
        }
    }
    float dv = dinv[r];
    unsigned int* orow = hs2 + (size_t)r * 16 + cb * 8;    // 16 bf16 = 8 uints
    #pragma unroll
    for (int j = 0; j < 4; ++j) {
        float4 a = acc[j];
        orow[2 * j]     = pack_bf2(a.x * dv, a.y * dv);
        orow[2 * j + 1] = pack_bf2(a.z * dv, a.w * dv);
    }
}

// One wave per node. 8 edge-groups x 8 lanes x (4 bf16 = 8B), unrolled x2. Fused head.
__global__ void k_agg2_head(const unsigned int* __restrict__ hs2, const int* __restrict__ csr,
                            const int* __restrict__ offsets, const int* __restrict__ count,
                            const float* __restrict__ dinv, const float* __restrict__ b2,
                            const float* __restrict__ Wfc, const float* __restrict__ bfc,
                            float* __restrict__ out, int n) {
    int wid = threadIdx.x >> 6;
    int lane = threadIdx.x & 63;
    int node = blockIdx.x * 4 + wid;
    if (node >= n) return;
    int g  = lane >> 3;
    int f4 = lane & 7;
    int s = offsets[node];
    int c = count[node];
    const uint2* tab = (const uint2*)hs2;

    float4 a0 = make_float4(0.f, 0.f, 0.f, 0.f);
    float4 a1 = make_float4(0.f, 0.f, 0.f, 0.f);
    if (g == 0) {
        uint2 sv = tab[(size_t)node * 8 + f4];
        a0 = make_float4(bf_lo(sv.x), bf_hi(sv.x), bf_lo(sv.y), bf_hi(sv.y));
    }

    for (int j = 0; j < c; j += 16) {
        int e0 = j + g;
        int e1 = j + 8 + g;
        int i0 = s + min(e0, c - 1);
        int i1 = s + min(e1, c - 1);
        int s0 = csr[i0];
        int s1 = csr[i1];
        float m0 = (e0 < c) ? 1.f : 0.f;
        float m1 = (e1 < c) ? 1.f : 0.f;
        uint2 u0 = tab[(size_t)s0 * 8 + f4];
        uint2 u1 = tab[(size_t)s1 * 8 + f4];
        a0.x = fmaf(m0, bf_lo(u0.x), a0.x); a0.y = fmaf(m0, bf_hi(u0.x), a0.y);
        a0.z = fmaf(m0, bf_lo(u0.y), a0.z); a0.w = fmaf(m0, bf_hi(u0.y), a0.w);
        a1.x = fmaf(m1, bf_lo(u1.x), a1.x); a1.y = fmaf(m1, bf_hi(u1.x), a1.y);
        a1.z = fmaf(m1, bf_lo(u1.y), a1.z); a1.w = fmaf(m1, bf_hi(u1.y), a1.w);
    }
    a0.x += a1.x; a0.y += a1.y; a0.z += a1.z; a0.w += a1.w;
    #pragma unroll
    for (int m = 8; m <= 32; m <<= 1) {
        a0.x += __shfl_xor(a0.x, m); a0.y += __shfl_xor(a0.y, m);
        a0.z += __shfl_xor(a0.z, m); a0.w += __shfl_xor(a0.w, m);
    }

    float dv = dinv[node];
    float4 b = ((const float4*)b2)[f4];
    float4 w = ((const float4*)Wfc)[f4];
    float hx = fmaxf(fmaf(dv, a0.x, b.x), 0.f);
    float hy = fmaxf(fmaf(dv, a0.y, b.y), 0.f);
    float hz = fmaxf(fmaf(dv, a0.z, b.z), 0.f);
    float hw = fmaxf(fmaf(dv, a0.w, b.w), 0.f);
    float p = hx * w.x + hy * w.y + hz * w.z + hw * w.w;
    p += __shfl_xor(p, 1);
    p += __shfl_xor(p, 2);
    p += __shfl_xor(p, 4);
    if (lane == 0) out[node] = p + bfc[0];
}

extern "C" void kernel_launch(void* const* d_in, const int* in_sizes, int n_in,
                              void* d_out, int out_size, void* d_ws, size_t ws_size,
                              hipStream_t stream) {
    const float* x   = (const float*)d_in[0];
    const void*  ei  = d_in[1];
    const float* W1  = (const float*)d_in[2];
    const float* b1  = (const float*)d_in[3];
    const float* W2  = (const float*)d_in[4];
    const float* b2  = (const float*)d_in[5];
    const float* Wfc = (const float*)d_in[6];
    const float* bfc = (const float*)d_in[7];
    float* out = (float*)d_out;

    const int n = in_sizes[0] / 128;                 // 100000
    const int E = in_sizes[1] / 2;                   // 1600000
    const int B = (n + 127) >> 7;                    // 782 buckets

    size_t off = 0;
    auto alloc = [&](size_t bytes) -> void* {
        void* p = (char*)d_ws + off;
        off += (bytes + 255) & ~(size_t)255;
        return p;
    };
    int*   bucket_count  = (int*)alloc((size_t)NBUCK_MAX * 4);
    int*   bucket_base   = (int*)alloc((size_t)NBUCK_MAX * 4);
    int*   bucket_cursor = (int*)alloc((size_t)NBUCK_MAX * 4);
    unsigned int* packed = (unsigned int*)alloc((size_t)E * 4);
    int*   csr     = (int*)  alloc((size_t)E * 4);
    int*   offsets = (int*)  alloc((size_t)n * 4);
    int*   count   = (int*)  alloc((size_t)n * 4);
    float* dinv    = (float*)alloc((size_t)n * 4);
    unsigned int* hs1    = (unsigned int*)alloc((size_t)n * 64 * 2);  // bf16
    unsigned int* h1post = (unsigned int*)alloc((size_t)n * 64 * 2);  // bf16
    unsigned int* hs2    = (unsigned int*)alloc((size_t)n * 32 * 2);  // bf16
    int*   flag    = (int*)  alloc(4);
    (void)ws_size;

    const int NB = (n + THREADS - 1) / THREADS;      // 391
    const int AG = (n + 3) / 4;

    k_detect_dtype<<<1, 1, 0, stream>>>((const unsigned int*)ei, flag);
    k_zero_int<<<(B + THREADS - 1) / THREADS, THREADS, 0, stream>>>(bucket_count, B);
    k_bucket_hist<<<SORT_BLOCKS, THREADS, 0, stream>>>(ei, flag, bucket_count, E, B);
    k_bucket_scan<<<1, 1024, 0, stream>>>(bucket_count, bucket_base, bucket_cursor, B);
    k_bucket_scatter<<<SORT_BLOCKS, THREADS, 0, stream>>>(ei, flag, bucket_cursor, packed, E, B);
    k_fine_sort<<<B, THREADS, 0, stream>>>(packed, bucket_base, bucket_count,
                                           csr, offsets, count, dinv, n, B);
    k_gemm1<<<dim3(NB, 2), THREADS, 0, stream>>>(x, W1, dinv, hs1, n);
    k_agg1<<<AG, THREADS, 0, stream>>>(hs1, csr, offsets, count, dinv, b1, h1post, n);
    k_gemm2<<<dim3(NB, 2), THREADS, 0, stream>>>(h1post, W2, dinv, hs2, n);
    k_agg2_head<<<AG, THREADS, 0, stream>>>(hs2, csr, offsets, count, dinv, b2, Wfc, bfc, out, n);
}